// Round 1
// baseline (1213.534 us; speedup 1.0000x reference)
//
#include <hip/hip_runtime.h>
#include <math.h>

// ---------------------------------------------------------------------------
// SimGNN forward on MI355X.
// Per graph: build dst-CSR (count/scan/fill), then
//   t1 = A x0            (agg64, 64-wide gather)
//   x1 = relu(t1@W1+b1)  (gemm64)
//   t2 = A x1            (agg64)
//   x2 = relu(t2@W2+b2)  (gemm64)
//   h3 = x2@W3           (gemm64_32, 64->32)
//   a3 = A h3 + b3       (agg32)
//   msum = colsum(a3); ctx = tanh(msum/N @ W_att)
//   pooled[j] = sum_n sigmoid(a3[n].ctx) * a3[n][j]
// Final: NTN(pooled1, pooled2) -> 16 floats.
// A is applied as: out[v] = dinv[v]*( x[v]*dinv[v] + sum_{(u->v)} x[u]*dinv[u] )
// ---------------------------------------------------------------------------

__global__ void count_kernel(const int* __restrict__ ei, int E, int* __restrict__ counts) {
    int i = blockIdx.x * blockDim.x + threadIdx.x;
    if (i < E) atomicAdd(&counts[ei[E + i]], 1);
}

// Single-block scan: row_ptr (exclusive prefix of counts) + dinv = rsqrt(deg+1).
__global__ void scan_kernel(const int* __restrict__ counts, int* __restrict__ row_ptr,
                            float* __restrict__ dinv, int N) {
    __shared__ int sdata[1024];
    int t = threadIdx.x;
    int per = (N + 1023) / 1024;
    int start = t * per; if (start > N) start = N;
    int end = start + per; if (end > N) end = N;
    int lsum = 0;
    for (int i = start; i < end; ++i) lsum += counts[i];
    sdata[t] = lsum;
    __syncthreads();
    for (int off = 1; off < 1024; off <<= 1) {
        int v = (t >= off) ? sdata[t - off] : 0;
        __syncthreads();
        sdata[t] += v;
        __syncthreads();
    }
    int run = (t == 0) ? 0 : sdata[t - 1];
    for (int i = start; i < end; ++i) {
        row_ptr[i] = run;
        int c = counts[i];
        run += c;
        dinv[i] = rsqrtf((float)(c + 1));
    }
    if (t == 1023) row_ptr[N] = sdata[1023];
}

__global__ void fill_kernel(const int* __restrict__ ei, int E, const int* __restrict__ row_ptr,
                            int* __restrict__ fill, int* __restrict__ col) {
    int i = blockIdx.x * blockDim.x + threadIdx.x;
    if (i < E) {
        int src = ei[i], dst = ei[E + i];
        int p = atomicAdd(&fill[dst], 1);
        col[row_ptr[dst] + p] = src;
    }
}

// One wave per node; lane = feature (64-wide).
__global__ void agg64_kernel(const float* __restrict__ x, float* __restrict__ out,
                             const int* __restrict__ row_ptr, const int* __restrict__ col,
                             const float* __restrict__ dinv, int N) {
    int gt = blockIdx.x * blockDim.x + threadIdx.x;
    int v = gt >> 6;
    int lane = gt & 63;
    if (v >= N) return;
    float dv = dinv[v];
    float acc = x[(size_t)v * 64 + lane] * dv;   // self-loop (final *dv gives dv^2)
    int s = row_ptr[v], e = row_ptr[v + 1];
    for (int i = s; i < e; ++i) {
        int u = col[i];
        acc += x[(size_t)u * 64 + lane] * dinv[u];
    }
    out[(size_t)v * 64 + lane] = acc * dv;
}

// Half-wave per node; lane = feature (32-wide). Adds bias (layer-3 epilogue).
__global__ void agg32_bias_kernel(const float* __restrict__ h, float* __restrict__ out,
                                  const int* __restrict__ row_ptr, const int* __restrict__ col,
                                  const float* __restrict__ dinv, const float* __restrict__ b,
                                  int N) {
    int gt = blockIdx.x * blockDim.x + threadIdx.x;
    int v = gt >> 5;
    int lane = gt & 31;
    if (v >= N) return;
    float dv = dinv[v];
    float acc = h[(size_t)v * 32 + lane] * dv;
    int s = row_ptr[v], e = row_ptr[v + 1];
    for (int i = s; i < e; ++i) {
        int u = col[i];
        acc += h[(size_t)u * 32 + lane] * dinv[u];
    }
    out[(size_t)v * 32 + lane] = acc * dv + b[lane];
}

// out[n][j] = act(sum_k in[n][k]*W[k][j] + b[j]); one wave per node, j = lane.
__global__ void gemm64_kernel(const float* __restrict__ in, float* __restrict__ out,
                              const float* __restrict__ W, const float* __restrict__ b,
                              int N, int relu) {
    __shared__ float Ws[64 * 64];
    for (int i = threadIdx.x; i < 64 * 64; i += blockDim.x) Ws[i] = W[i];
    __syncthreads();
    int node = blockIdx.x * 4 + (threadIdx.x >> 6);
    int j = threadIdx.x & 63;
    if (node >= N) return;
    const float* row = in + (size_t)node * 64;
    float r = row[j];                       // one vector load; broadcast via shfl
    float acc = b[j];
    #pragma unroll
    for (int k = 0; k < 64; ++k) acc += __shfl(r, k) * Ws[k * 64 + j];
    if (relu) acc = fmaxf(acc, 0.f);
    out[(size_t)node * 64 + j] = acc;
}

// 64 -> 32, no bias/act (bias folded into agg32). Half-wave per node.
__global__ void gemm64_32_kernel(const float* __restrict__ in, float* __restrict__ out,
                                 const float* __restrict__ W, int N) {
    __shared__ float Ws[64 * 32];
    for (int i = threadIdx.x; i < 64 * 32; i += blockDim.x) Ws[i] = W[i];
    __syncthreads();
    int half = (blockIdx.x * blockDim.x + threadIdx.x) >> 5;
    int j = threadIdx.x & 31;
    if (half >= N) return;
    const float* row = in + (size_t)half * 64;
    float r0 = row[j], r1 = row[j + 32];
    float acc = 0.f;
    #pragma unroll
    for (int k = 0; k < 32; ++k) {
        acc += __shfl(r0, k, 32) * Ws[k * 32 + j];
        acc += __shfl(r1, k, 32) * Ws[(k + 32) * 32 + j];
    }
    out[(size_t)half * 32 + j] = acc;
}

// Column sums of a3 [N,32] -> msum[32] (block partials + one atomic per block).
__global__ void colsum_kernel(const float* __restrict__ a3, float* __restrict__ msum, int N) {
    int t = threadIdx.x;
    int j = t & 31;
    int hw = (blockIdx.x * blockDim.x + t) >> 5;
    int nhw = (gridDim.x * blockDim.x) >> 5;
    float local = 0.f;
    for (int n = hw; n < N; n += nhw) local += a3[(size_t)n * 32 + j];
    __shared__ float sp[256];
    sp[t] = local;
    __syncthreads();
    if (t < 32) {
        float s = 0.f;
        for (int w = 0; w < 8; ++w) s += sp[w * 32 + t];
        atomicAdd(&msum[t], s);
    }
}

// ctx[j] = tanh( sum_i (msum[i]/N) * W_att[i][j] ), one wave.
__global__ void ctx_kernel(const float* __restrict__ msum, const float* __restrict__ W_att,
                           float* __restrict__ ctx, int N) {
    int j = threadIdx.x;
    if (j >= 32) return;
    float invN = 1.f / (float)N;
    float acc = 0.f;
    for (int i = 0; i < 32; ++i) acc += (msum[i] * invN) * W_att[i * 32 + j];
    ctx[j] = tanhf(acc);
}

// pooled[j] = sum_n sigmoid(a3[n].ctx) * a3[n][j]
__global__ void pool_kernel(const float* __restrict__ a3, const float* __restrict__ ctx,
                            float* __restrict__ pooled, int N) {
    int t = threadIdx.x;
    int j = t & 31;
    int hw = (blockIdx.x * blockDim.x + t) >> 5;
    int nhw = (gridDim.x * blockDim.x) >> 5;
    float cj = ctx[j];
    float local = 0.f;
    for (int n = hw; n < N; n += nhw) {
        float v = a3[(size_t)n * 32 + j];
        float d = v * cj;
        #pragma unroll
        for (int off = 16; off; off >>= 1) d += __shfl_xor(d, off);  // masks<=16 stay in 32-lane half
        float s = 1.f / (1.f + __expf(-d));
        local += s * v;
    }
    __shared__ float sp[256];
    sp[t] = local;
    __syncthreads();
    if (t < 32) {
        float s = 0.f;
        for (int w = 0; w < 8; ++w) s += sp[w * 32 + t];
        atomicAdd(&pooled[t], s);
    }
}

// NTN: out[k] = relu( sum_ij e1[i] W_tn[i,j,k] e2[j] + W_block[k].[e1;e2] + b_tn[k] )
__global__ void ntn_kernel(const float* __restrict__ p1, const float* __restrict__ p2,
                           const float* __restrict__ W_tn, const float* __restrict__ W_block,
                           const float* __restrict__ b_tn, float* __restrict__ out) {
    int k = threadIdx.x;
    if (k >= 16) return;
    float sc = 0.f;
    for (int i = 0; i < 32; ++i) {
        float e1 = p1[i];
        for (int j = 0; j < 32; ++j) sc += e1 * W_tn[i * 512 + j * 16 + k] * p2[j];
    }
    float bl = 0.f;
    for (int j = 0; j < 32; ++j)
        bl += W_block[k * 64 + j] * p1[j] + W_block[k * 64 + 32 + j] * p2[j];
    float v = sc + bl + b_tn[k];
    out[k] = v > 0.f ? v : 0.f;
}

extern "C" void kernel_launch(void* const* d_in, const int* in_sizes, int n_in,
                              void* d_out, int out_size, void* d_ws, size_t ws_size,
                              hipStream_t stream) {
    const float* f1     = (const float*)d_in[0];
    const int*   ei1    = (const int*)  d_in[1];
    const float* f2     = (const float*)d_in[2];
    const int*   ei2    = (const int*)  d_in[3];
    const float* W1     = (const float*)d_in[4];
    const float* b1     = (const float*)d_in[5];
    const float* W2     = (const float*)d_in[6];
    const float* b2     = (const float*)d_in[7];
    const float* W3     = (const float*)d_in[8];
    const float* b3     = (const float*)d_in[9];
    const float* W_att  = (const float*)d_in[10];
    const float* W_tn   = (const float*)d_in[11];
    const float* W_blk  = (const float*)d_in[12];
    const float* b_tn   = (const float*)d_in[13];

    int N = in_sizes[0] / 64;
    int E = in_sizes[1] / 2;

    char* ws = (char*)d_ws;
    size_t off = 0;
    auto alloc = [&](size_t bytes) -> void* {
        void* p = ws + off;
        off += (bytes + 511) & ~(size_t)511;
        return p;
    };
    float* bufA    = (float*)alloc((size_t)N * 64 * sizeof(float));
    float* bufB    = (float*)alloc((size_t)N * 64 * sizeof(float));
    int*   col     = (int*)  alloc((size_t)E * sizeof(int));
    int*   row_ptr = (int*)  alloc((size_t)(N + 1) * sizeof(int));
    int*   counts  = (int*)  alloc((size_t)N * 2 * sizeof(int));  // counts + fill adjacent
    int*   fillc   = counts + N;
    float* dinv    = (float*)alloc((size_t)N * sizeof(float));
    float* smalls  = (float*)alloc(256 * sizeof(float));
    float* msum1 = smalls,        * msum2   = smalls + 32;
    float* pool1 = smalls + 64,   * pool2   = smalls + 96;
    float* ctx1  = smalls + 128,  * ctx2    = smalls + 160;

    hipMemsetAsync(smalls, 0, 256 * sizeof(float), stream);

    int eb   = (E + 255) / 256;
    int nb64 = (N * 64 + 255) / 256;  // wave-per-node
    int nb4  = (N + 3) / 4;           // gemm64: 4 nodes/block
    int nb32 = (N * 32 + 255) / 256;  // half-wave-per-node

    for (int g = 0; g < 2; ++g) {
        const float* feat = g ? f2 : f1;
        const int*   ei   = g ? ei2 : ei1;
        float* msum   = g ? msum2 : msum1;
        float* pooled = g ? pool2 : pool1;
        float* ctx    = g ? ctx2  : ctx1;

        hipMemsetAsync(counts, 0, (size_t)N * 2 * sizeof(int), stream);
        count_kernel<<<eb, 256, 0, stream>>>(ei, E, counts);
        scan_kernel<<<1, 1024, 0, stream>>>(counts, row_ptr, dinv, N);
        fill_kernel<<<eb, 256, 0, stream>>>(ei, E, row_ptr, fillc, col);

        agg64_kernel<<<nb64, 256, 0, stream>>>(feat, bufA, row_ptr, col, dinv, N);
        gemm64_kernel<<<nb4, 256, 0, stream>>>(bufA, bufB, W1, b1, N, 1);
        agg64_kernel<<<nb64, 256, 0, stream>>>(bufB, bufA, row_ptr, col, dinv, N);
        gemm64_kernel<<<nb4, 256, 0, stream>>>(bufA, bufB, W2, b2, N, 1);
        gemm64_32_kernel<<<nb32, 256, 0, stream>>>(bufB, bufA, W3, N);
        agg32_bias_kernel<<<nb32, 256, 0, stream>>>(bufA, bufB, row_ptr, col, dinv, b3, N);
        colsum_kernel<<<256, 256, 0, stream>>>(bufB, msum, N);
        ctx_kernel<<<1, 64, 0, stream>>>(msum, W_att, ctx, N);
        pool_kernel<<<256, 256, 0, stream>>>(bufB, ctx, pooled, N);
    }
    ntn_kernel<<<1, 64, 0, stream>>>(pool1, pool2, W_tn, W_blk, b_tn, (float*)d_out);
}

// Round 2
// 762.037 us; speedup vs baseline: 1.5925x; 1.5925x over previous
//
#include <hip/hip_runtime.h>
#include <math.h>

// ---------------------------------------------------------------------------
// SimGNN forward on MI355X — combined-graph pipeline.
// Both graphs share GCN weights, so we concatenate them: M = 2N nodes,
// graph-2 node ids offset by +N. One CSR build + one pass per layer.
//   t1 = A x0            (agg64; x0 rows come from f1/f2 by halves)
//   x1 = relu(t1@W1+b1)  (gemm64)
//   t2 = A x1            (agg64)
//   x2 = relu(t2@W2+b2)  (gemm64)
//   h3 = x2@W3           (gemm64_32)
//   a3 = A h3 + b3       (agg32)
//   per graph: msum -> ctx = tanh(msum/N @ W_att) -> pooled
//   NTN(pooled1, pooled2) -> 16 floats.
// A applied as out[v] = dinv[v]*( x[v]*dinv[v] + sum_{(u->v)} x[u]*dinv[u] );
// per-edge nrm[i] = dinv[src] is precomputed in fill so the agg inner loop
// has a single dependent gather (col[i] -> x row), unrolled x4.
// ---------------------------------------------------------------------------

__global__ void count2_kernel(const int* __restrict__ ei1, const int* __restrict__ ei2,
                              int E, int N, int* __restrict__ counts) {
    int i = blockIdx.x * blockDim.x + threadIdx.x;
    if (i < E)          atomicAdd(&counts[ei1[E + i]], 1);
    else if (i < 2 * E) atomicAdd(&counts[ei2[E + (i - E)] + N], 1);
}

// ---- 3-phase scan over counts[M] -> row_ptr[M+1], dinv[M] ----
// chunk = 1024 elements per block (256 threads x 4).
__global__ void scanA_kernel(const int* __restrict__ counts, int* __restrict__ bsum, int M) {
    __shared__ int sh[256];
    int t = threadIdx.x;
    int base = blockIdx.x * 1024 + t * 4;
    int s = 0;
    #pragma unroll
    for (int k = 0; k < 4; ++k) { int idx = base + k; if (idx < M) s += counts[idx]; }
    sh[t] = s;
    __syncthreads();
    for (int off = 128; off; off >>= 1) {
        if (t < off) sh[t] += sh[t + off];
        __syncthreads();
    }
    if (t == 0) bsum[blockIdx.x] = sh[0];
}

// One block: exclusive scan of bsum[P] in place; row_ptr[M] = total.
__global__ void scanB_kernel(int* __restrict__ bsum, int P, int* __restrict__ row_ptr, int M) {
    __shared__ int sh[256];
    int t = threadIdx.x;
    sh[t] = (t < P) ? bsum[t] : 0;
    __syncthreads();
    for (int off = 1; off < 256; off <<= 1) {
        int v = (t >= off) ? sh[t - off] : 0;
        __syncthreads();
        sh[t] += v;
        __syncthreads();
    }
    if (t < P) bsum[t] = (t == 0) ? 0 : sh[t - 1];
    if (t == 255) row_ptr[M] = sh[255];
}

__global__ void scanC_kernel(const int* __restrict__ counts, const int* __restrict__ bsum,
                             int* __restrict__ row_ptr, float* __restrict__ dinv, int M) {
    __shared__ int sh[256];
    int t = threadIdx.x;
    int base = blockIdx.x * 1024 + t * 4;
    int c[4];
    int s = 0;
    #pragma unroll
    for (int k = 0; k < 4; ++k) { int idx = base + k; c[k] = (idx < M) ? counts[idx] : 0; s += c[k]; }
    sh[t] = s;
    __syncthreads();
    for (int off = 1; off < 256; off <<= 1) {
        int v = (t >= off) ? sh[t - off] : 0;
        __syncthreads();
        sh[t] += v;
        __syncthreads();
    }
    int run = bsum[blockIdx.x] + ((t == 0) ? 0 : sh[t - 1]);
    #pragma unroll
    for (int k = 0; k < 4; ++k) {
        int idx = base + k;
        if (idx < M) {
            row_ptr[idx] = run;
            dinv[idx] = rsqrtf((float)(c[k] + 1));
            run += c[k];
        }
    }
}

// counts doubles as the per-row cursor: atomicSub returns remaining slot count.
__global__ void fill2_kernel(const int* __restrict__ ei1, const int* __restrict__ ei2,
                             int E, int N, const int* __restrict__ row_ptr,
                             int* __restrict__ counts, const float* __restrict__ dinv,
                             int* __restrict__ col, float* __restrict__ nrm) {
    int i = blockIdx.x * blockDim.x + threadIdx.x;
    int src, dst;
    if (i < E)          { src = ei1[i];             dst = ei1[E + i]; }
    else if (i < 2 * E) { src = ei2[i - E] + N;     dst = ei2[E + (i - E)] + N; }
    else return;
    int p = atomicSub(&counts[dst], 1) - 1;
    int pos = row_ptr[dst] + p;
    col[pos] = src;
    nrm[pos] = dinv[src];
}

// One wave per node; lane = feature (64-wide). Input rows selected via base
// pointer trick: for v < N rows come from x1[v], else x2 - N*64 (so a combined
// buffer works by passing x1=buf, x2=buf+N*64).
__global__ void agg64_kernel(const float* __restrict__ x1, const float* __restrict__ x2,
                             float* __restrict__ out, const int* __restrict__ row_ptr,
                             const int* __restrict__ col, const float* __restrict__ nrm,
                             const float* __restrict__ dinv, int N, int M) {
    int gt = blockIdx.x * blockDim.x + threadIdx.x;
    int v = gt >> 6;
    int lane = gt & 63;
    if (v >= M) return;
    const float* xb = (v < N) ? x1 : (x2 - (size_t)N * 64);
    float dv = dinv[v];
    float acc = xb[(size_t)v * 64 + lane] * dv;   // self-loop (final *dv gives dv^2)
    int s = row_ptr[v], e = row_ptr[v + 1];
    int i = s;
    for (; i + 4 <= e; i += 4) {
        int u0 = col[i], u1 = col[i + 1], u2 = col[i + 2], u3 = col[i + 3];
        float w0 = nrm[i], w1 = nrm[i + 1], w2 = nrm[i + 2], w3 = nrm[i + 3];
        float a0 = xb[(size_t)u0 * 64 + lane];
        float a1 = xb[(size_t)u1 * 64 + lane];
        float a2 = xb[(size_t)u2 * 64 + lane];
        float a3 = xb[(size_t)u3 * 64 + lane];
        acc += a0 * w0 + a1 * w1 + a2 * w2 + a3 * w3;
    }
    for (; i < e; ++i) acc += xb[(size_t)col[i] * 64 + lane] * nrm[i];
    out[(size_t)v * 64 + lane] = acc * dv;
}

// Half-wave per node; lane = feature (32-wide). Adds bias (layer-3 epilogue).
__global__ void agg32_bias_kernel(const float* __restrict__ h, float* __restrict__ out,
                                  const int* __restrict__ row_ptr, const int* __restrict__ col,
                                  const float* __restrict__ nrm, const float* __restrict__ dinv,
                                  const float* __restrict__ b, int M) {
    int gt = blockIdx.x * blockDim.x + threadIdx.x;
    int v = gt >> 5;
    int lane = gt & 31;
    if (v >= M) return;
    float dv = dinv[v];
    float acc = h[(size_t)v * 32 + lane] * dv;
    int s = row_ptr[v], e = row_ptr[v + 1];
    int i = s;
    for (; i + 4 <= e; i += 4) {
        int u0 = col[i], u1 = col[i + 1], u2 = col[i + 2], u3 = col[i + 3];
        float w0 = nrm[i], w1 = nrm[i + 1], w2 = nrm[i + 2], w3 = nrm[i + 3];
        acc += h[(size_t)u0 * 32 + lane] * w0 + h[(size_t)u1 * 32 + lane] * w1
             + h[(size_t)u2 * 32 + lane] * w2 + h[(size_t)u3 * 32 + lane] * w3;
    }
    for (; i < e; ++i) acc += h[(size_t)col[i] * 32 + lane] * nrm[i];
    out[(size_t)v * 32 + lane] = acc * dv + b[lane];
}

// out[n][j] = act(sum_k in[n][k]*W[k][j] + b[j]); one wave per node, j = lane.
__global__ void gemm64_kernel(const float* __restrict__ in, float* __restrict__ out,
                              const float* __restrict__ W, const float* __restrict__ b,
                              int M, int relu) {
    __shared__ float Ws[64 * 64];
    for (int i = threadIdx.x; i < 64 * 64; i += blockDim.x) Ws[i] = W[i];
    __syncthreads();
    int node = blockIdx.x * 4 + (threadIdx.x >> 6);
    int j = threadIdx.x & 63;
    if (node >= M) return;
    const float* row = in + (size_t)node * 64;
    float r = row[j];                       // one coalesced load; broadcast via shfl
    float acc = b[j];
    #pragma unroll
    for (int k = 0; k < 64; ++k) acc += __shfl(r, k) * Ws[k * 64 + j];
    if (relu) acc = fmaxf(acc, 0.f);
    out[(size_t)node * 64 + j] = acc;
}

// 64 -> 32, no bias/act (bias folded into agg32). Half-wave per node.
__global__ void gemm64_32_kernel(const float* __restrict__ in, float* __restrict__ out,
                                 const float* __restrict__ W, int M) {
    __shared__ float Ws[64 * 32];
    for (int i = threadIdx.x; i < 64 * 32; i += blockDim.x) Ws[i] = W[i];
    __syncthreads();
    int half = (blockIdx.x * blockDim.x + threadIdx.x) >> 5;
    int j = threadIdx.x & 31;
    if (half >= M) return;
    const float* row = in + (size_t)half * 64;
    float r0 = row[j], r1 = row[j + 32];
    float acc = 0.f;
    #pragma unroll
    for (int k = 0; k < 32; ++k) {
        acc += __shfl(r0, k, 32) * Ws[k * 32 + j];
        acc += __shfl(r1, k, 32) * Ws[(k + 32) * 32 + j];
    }
    out[(size_t)half * 32 + j] = acc;
}

// Column sums of a3 halves -> msum[g*32+j]. gridDim = 512; blocks [0,256) do
// graph 0, [256,512) graph 1.
__global__ void colsum2_kernel(const float* __restrict__ a3, float* __restrict__ msum, int N) {
    int g = blockIdx.x >> 8;
    int bid = blockIdx.x & 255;
    int t = threadIdx.x;
    int j = t & 31;
    int hw = (bid * 256 + t) >> 5;
    const int nhw = (256 * 256) >> 5;
    const float* base = a3 + (size_t)g * N * 32;
    float local = 0.f;
    for (int n = hw; n < N; n += nhw) local += base[(size_t)n * 32 + j];
    __shared__ float sp[256];
    sp[t] = local;
    __syncthreads();
    if (t < 32) {
        float s = 0.f;
        for (int w = 0; w < 8; ++w) s += sp[w * 32 + t];
        atomicAdd(&msum[g * 32 + t], s);
    }
}

// ctx[g*32+j] = tanh( sum_i (msum[g*32+i]/N) * W_att[i][j] ); one 64-thread block.
__global__ void ctx2_kernel(const float* __restrict__ msum, const float* __restrict__ W_att,
                            float* __restrict__ ctx, int N) {
    int t = threadIdx.x;
    if (t >= 64) return;
    int g = t >> 5, j = t & 31;
    float invN = 1.f / (float)N;
    float acc = 0.f;
    for (int i = 0; i < 32; ++i) acc += (msum[g * 32 + i] * invN) * W_att[i * 32 + j];
    ctx[g * 32 + j] = tanhf(acc);
}

// pooled[g*32+j] = sum_n sigmoid(a3[n].ctx_g) * a3[n][j]; same grid split.
__global__ void pool2_kernel(const float* __restrict__ a3, const float* __restrict__ ctx,
                             float* __restrict__ pooled, int N) {
    int g = blockIdx.x >> 8;
    int bid = blockIdx.x & 255;
    int t = threadIdx.x;
    int j = t & 31;
    int hw = (bid * 256 + t) >> 5;
    const int nhw = (256 * 256) >> 5;
    const float* base = a3 + (size_t)g * N * 32;
    float cj = ctx[g * 32 + j];
    float local = 0.f;
    for (int n = hw; n < N; n += nhw) {
        float v = base[(size_t)n * 32 + j];
        float d = v * cj;
        #pragma unroll
        for (int off = 16; off; off >>= 1) d += __shfl_xor(d, off);  // masks<=16 stay in 32-lane half
        float s = 1.f / (1.f + __expf(-d));
        local += s * v;
    }
    __shared__ float sp[256];
    sp[t] = local;
    __syncthreads();
    if (t < 32) {
        float s = 0.f;
        for (int w = 0; w < 8; ++w) s += sp[w * 32 + t];
        atomicAdd(&pooled[g * 32 + t], s);
    }
}

// NTN: out[k] = relu( sum_ij e1[i] W_tn[i,j,k] e2[j] + W_block[k].[e1;e2] + b_tn[k] )
__global__ void ntn_kernel(const float* __restrict__ p1, const float* __restrict__ p2,
                           const float* __restrict__ W_tn, const float* __restrict__ W_block,
                           const float* __restrict__ b_tn, float* __restrict__ out) {
    int k = threadIdx.x;
    if (k >= 16) return;
    float sc = 0.f;
    for (int i = 0; i < 32; ++i) {
        float e1 = p1[i];
        for (int j = 0; j < 32; ++j) sc += e1 * W_tn[i * 512 + j * 16 + k] * p2[j];
    }
    float bl = 0.f;
    for (int j = 0; j < 32; ++j)
        bl += W_block[k * 64 + j] * p1[j] + W_block[k * 64 + 32 + j] * p2[j];
    float v = sc + bl + b_tn[k];
    out[k] = v > 0.f ? v : 0.f;
}

extern "C" void kernel_launch(void* const* d_in, const int* in_sizes, int n_in,
                              void* d_out, int out_size, void* d_ws, size_t ws_size,
                              hipStream_t stream) {
    const float* f1     = (const float*)d_in[0];
    const int*   ei1    = (const int*)  d_in[1];
    const float* f2     = (const float*)d_in[2];
    const int*   ei2    = (const int*)  d_in[3];
    const float* W1     = (const float*)d_in[4];
    const float* b1     = (const float*)d_in[5];
    const float* W2     = (const float*)d_in[6];
    const float* b2     = (const float*)d_in[7];
    const float* W3     = (const float*)d_in[8];
    const float* b3     = (const float*)d_in[9];
    const float* W_att  = (const float*)d_in[10];
    const float* W_tn   = (const float*)d_in[11];
    const float* W_blk  = (const float*)d_in[12];
    const float* b_tn   = (const float*)d_in[13];

    int N = in_sizes[0] / 64;
    int E = in_sizes[1] / 2;
    int M = 2 * N;          // combined node count
    int E2 = 2 * E;         // combined edge count

    char* ws = (char*)d_ws;
    size_t off = 0;
    auto alloc = [&](size_t bytes) -> void* {
        void* p = ws + off;
        off += (bytes + 511) & ~(size_t)511;
        return p;
    };
    float* bufA    = (float*)alloc((size_t)M * 64 * sizeof(float));
    float* bufB    = (float*)alloc((size_t)M * 64 * sizeof(float));
    int*   col     = (int*)  alloc((size_t)E2 * sizeof(int));
    float* nrm     = (float*)alloc((size_t)E2 * sizeof(float));
    int*   row_ptr = (int*)  alloc((size_t)(M + 1) * sizeof(int));
    int*   counts  = (int*)  alloc((size_t)M * sizeof(int));
    float* dinv    = (float*)alloc((size_t)M * sizeof(float));
    int*   bsum    = (int*)  alloc(256 * sizeof(int));
    float* smalls  = (float*)alloc(256 * sizeof(float));
    float* msum   = smalls;        // [64]  (two graphs x 32)
    float* pooled = smalls + 64;   // [64]
    float* ctx    = smalls + 128;  // [64]

    hipMemsetAsync(smalls, 0, 256 * sizeof(float), stream);
    hipMemsetAsync(counts, 0, (size_t)M * sizeof(int), stream);

    int eb   = (E2 + 255) / 256;
    int nb64 = (M * 64 + 255) / 256;      // wave-per-node
    int nb4  = (M + 3) / 4;               // gemm64: 4 nodes/block
    int nb32 = (M * 32 + 255) / 256;      // half-wave-per-node
    int P    = (M + 1023) / 1024;         // scan chunks

    // CSR build (combined)
    count2_kernel<<<eb, 256, 0, stream>>>(ei1, ei2, E, N, counts);
    scanA_kernel<<<P, 256, 0, stream>>>(counts, bsum, M);
    scanB_kernel<<<1, 256, 0, stream>>>(bsum, P, row_ptr, M);
    scanC_kernel<<<P, 256, 0, stream>>>(counts, bsum, row_ptr, dinv, M);
    fill2_kernel<<<eb, 256, 0, stream>>>(ei1, ei2, E, N, row_ptr, counts, dinv, col, nrm);

    // GCN stack on combined graph
    agg64_kernel<<<nb64, 256, 0, stream>>>(f1, f2, bufA, row_ptr, col, nrm, dinv, N, M);
    gemm64_kernel<<<nb4, 256, 0, stream>>>(bufA, bufB, W1, b1, M, 1);
    agg64_kernel<<<nb64, 256, 0, stream>>>(bufB, bufB + (size_t)N * 64, bufA, row_ptr, col, nrm, dinv, N, M);
    gemm64_kernel<<<nb4, 256, 0, stream>>>(bufA, bufB, W2, b2, M, 1);
    gemm64_32_kernel<<<nb32, 256, 0, stream>>>(bufB, bufA, W3, M);
    agg32_bias_kernel<<<nb32, 256, 0, stream>>>(bufA, bufB, row_ptr, col, nrm, dinv, b3, M);

    // Per-graph attention pooling + NTN
    colsum2_kernel<<<512, 256, 0, stream>>>(bufB, msum, N);
    ctx2_kernel<<<1, 64, 0, stream>>>(msum, W_att, ctx, N);
    pool2_kernel<<<512, 256, 0, stream>>>(bufB, ctx, pooled, N);
    ntn_kernel<<<1, 64, 0, stream>>>(pooled, pooled + 32, W_tn, W_blk, b_tn, (float*)d_out);
}